// Round 2
// baseline (878.928 us; speedup 1.0000x reference)
//
#include <hip/hip_runtime.h>

// Problem constants (match the reference setup)
constexpr int B_ = 8, C_ = 4, D_ = 64, H_ = 256, W_ = 256;
constexpr int W4_ = W_ / 4;                    // 64 vec4 per row
constexpr int PLANE4 = H_ * W4_;               // 16384 vec4 per (b,c,d) plane
constexpr int VOL4 = D_ * PLANE4;              // 2^20 vec4 per (b,c)

__global__ __launch_bounds__(256) void shift3d_kernel(
    const float* __restrict__ x,
    const int* __restrict__ dims,
    const int* __restrict__ shifts,
    const int* __restrict__ signs,
    const int* __restrict__ apply_mask,
    float* __restrict__ out)
{
    // One block per (b,c,d) plane: grid = 8*4*64 = 2048 blocks.
    const int bcd = blockIdx.x;
    const int bc  = bcd >> 6;           // D_ == 64
    const int d   = bcd & (D_ - 1);

    // Wave-uniform per-(b,c) parameters, loaded once.
    const int dim   = dims[bc];
    const int shift = shifts[bc];
    const int sign  = signs[bc];
    const int apply = apply_mask[bc >> 2];   // b = bc / C_, C_ == 4

    const float4* __restrict__ src = (const float4*)x + (size_t)bc * VOL4;
    float4* __restrict__ dst = (float4*)out + (size_t)bc * VOL4 + d * PLANE4;
    const int tid = threadIdx.x;

    if (apply <= 0) {                                   // identity copy
        const float4* sp = src + d * PLANE4;
        for (int i = tid; i < PLANE4; i += 256) dst[i] = sp[i];
        return;
    }

    const int s = sign * shift;                         // signed roll amount

    if (dim == 0) {                                     // roll along D (n=64)
        const bool pad = (sign == 1) ? (d < shift) : (d >= D_ - shift);
        if (pad) {
            const float4 z = make_float4(0.f, 0.f, 0.f, 0.f);
            for (int i = tid; i < PLANE4; i += 256) dst[i] = z;
        } else {
            const int sd = (d - s) & (D_ - 1);          // pow2 modular wrap
            const float4* sp = src + sd * PLANE4;
            for (int i = tid; i < PLANE4; i += 256) dst[i] = sp[i];
        }
    } else if (dim == 1) {                              // roll along H (n=256)
        const float4* sp = src + d * PLANE4;
        const float4 z = make_float4(0.f, 0.f, 0.f, 0.f);
        for (int i = tid; i < PLANE4; i += 256) {
            const int h  = i >> 6;                      // W4_ == 64
            const int w4 = i & (W4_ - 1);
            const bool pad = (sign == 1) ? (h < shift) : (h >= H_ - shift);
            float4 v = z;
            if (!pad) {
                const int sh = (h - s) & (H_ - 1);
                v = sp[(sh << 6) | w4];
            }
            dst[i] = v;
        }
    } else {                                            // roll along W (n=256)
        const float* row_base = (const float*)src + ((size_t)d << 16);  // d*H*W
        for (int i = tid; i < PLANE4; i += 256) {
            const int h  = i >> 6;
            const int w0 = (i & (W4_ - 1)) << 2;
            const float* row = row_base + (h << 8);
            float4 r;
            float* rp = (float*)&r;
            #pragma unroll
            for (int k = 0; k < 4; ++k) {
                const int w = w0 + k;
                const bool pad = (sign == 1) ? (w < shift) : (w >= W_ - shift);
                rp[k] = pad ? 0.0f : row[(w - s) & (W_ - 1)];
            }
            dst[i] = r;
        }
    }
}

extern "C" void kernel_launch(void* const* d_in, const int* in_sizes, int n_in,
                              void* d_out, int out_size, void* d_ws, size_t ws_size,
                              hipStream_t stream) {
    const float* x          = (const float*)d_in[0];
    const int*   dims       = (const int*)d_in[1];
    const int*   shifts     = (const int*)d_in[2];
    const int*   signs      = (const int*)d_in[3];
    const int*   apply_mask = (const int*)d_in[4];
    float* out = (float*)d_out;

    dim3 grid(B_ * C_ * D_), block(256);                // 2048 blocks
    shift3d_kernel<<<grid, block, 0, stream>>>(x, dims, shifts, signs, apply_mask, out);
}

// Round 8
// 864.005 us; speedup vs baseline: 1.0173x; 1.0173x over previous
//
#include <hip/hip_runtime.h>

// Problem constants (match the reference setup)
constexpr int B_ = 8, C_ = 4, D_ = 64, H_ = 256, W_ = 256;
constexpr int W4_ = W_ / 4;                    // 64 vec4 per row
constexpr int PLANE4 = H_ * W4_;               // 16384 vec4 per (b,c,d) plane
constexpr int VOL4 = D_ * PLANE4;              // 2^20 vec4 per (b,c)

using f4 = __attribute__((ext_vector_type(4))) float;

__device__ __forceinline__ void copy_plane_nt(f4* __restrict__ dst,
                                              const f4* __restrict__ sp,
                                              int tid) {
    #pragma unroll 4
    for (int base = 0; base < PLANE4; base += 1024) {
        const int i0 = base + tid;
        f4 a = __builtin_nontemporal_load(&sp[i0]);
        f4 b = __builtin_nontemporal_load(&sp[i0 + 256]);
        f4 c = __builtin_nontemporal_load(&sp[i0 + 512]);
        f4 e = __builtin_nontemporal_load(&sp[i0 + 768]);
        __builtin_nontemporal_store(a, &dst[i0]);
        __builtin_nontemporal_store(b, &dst[i0 + 256]);
        __builtin_nontemporal_store(c, &dst[i0 + 512]);
        __builtin_nontemporal_store(e, &dst[i0 + 768]);
    }
}

__global__ __launch_bounds__(256) void shift3d_kernel(
    const float* __restrict__ x,
    const int* __restrict__ dims,
    const int* __restrict__ shifts,
    const int* __restrict__ signs,
    const int* __restrict__ apply_mask,
    float* __restrict__ out)
{
    // One block per (b,c,d) plane: grid = 8*4*64 = 2048 blocks.
    const int bcd = blockIdx.x;
    const int bc  = bcd >> 6;           // D_ == 64
    const int d   = bcd & (D_ - 1);

    // Wave-uniform per-(b,c) parameters, loaded once.
    const int dim   = dims[bc];
    const int shift = shifts[bc];
    const int sign  = signs[bc];
    const int apply = apply_mask[bc >> 2];   // b = bc / C_, C_ == 4

    const f4* __restrict__ src = (const f4*)x + (size_t)bc * VOL4;
    f4* __restrict__ dst = (f4*)out + (size_t)bc * VOL4 + d * PLANE4;
    const int tid = threadIdx.x;
    const f4 z = (f4)0.0f;

    if (apply <= 0) {                                   // identity copy
        copy_plane_nt(dst, src + d * PLANE4, tid);
        return;
    }

    const int s = sign * shift;                         // signed roll amount

    if (dim == 0) {                                     // roll along D (n=64)
        const bool pad = (sign == 1) ? (d < shift) : (d >= D_ - shift);
        if (pad) {
            #pragma unroll 4
            for (int base = 0; base < PLANE4; base += 1024) {
                const int i0 = base + tid;
                __builtin_nontemporal_store(z, &dst[i0]);
                __builtin_nontemporal_store(z, &dst[i0 + 256]);
                __builtin_nontemporal_store(z, &dst[i0 + 512]);
                __builtin_nontemporal_store(z, &dst[i0 + 768]);
            }
        } else {
            const int sd = (d - s) & (D_ - 1);          // pow2 modular wrap
            copy_plane_nt(dst, src + sd * PLANE4, tid);
        }
    } else if (dim == 1) {                              // roll along H (n=256)
        const f4* sp = src + d * PLANE4;
        for (int base = 0; base < PLANE4; base += 1024) {
            f4 v[4];
            #pragma unroll
            for (int k = 0; k < 4; ++k) {
                const int i  = base + tid + k * 256;
                const int h  = i >> 6;                  // W4_ == 64
                const int w4 = i & (W4_ - 1);
                const bool pad = (sign == 1) ? (h < shift) : (h >= H_ - shift);
                const int sh = (h - s) & (H_ - 1);
                v[k] = pad ? z : __builtin_nontemporal_load(&sp[(sh << 6) | w4]);
            }
            #pragma unroll
            for (int k = 0; k < 4; ++k)
                __builtin_nontemporal_store(v[k], &dst[base + tid + k * 256]);
        }
    } else {                                            // roll along W (n=256)
        const float* row_base = (const float*)src + ((size_t)d << 16);  // d*H*W
        for (int base = 0; base < PLANE4; base += 512) {
            f4 v[2];
            #pragma unroll
            for (int k = 0; k < 2; ++k) {
                const int i  = base + tid + k * 256;
                const int h  = i >> 6;
                const int w0 = (i & (W4_ - 1)) << 2;
                const float* row = row_base + (h << 8);
                #pragma unroll
                for (int e = 0; e < 4; ++e) {
                    const int w = w0 + e;
                    const bool pad = (sign == 1) ? (w < shift) : (w >= W_ - shift);
                    v[k][e] = pad ? 0.0f
                                  : __builtin_nontemporal_load(&row[(w - s) & (W_ - 1)]);
                }
            }
            #pragma unroll
            for (int k = 0; k < 2; ++k)
                __builtin_nontemporal_store(v[k], &dst[base + tid + k * 256]);
        }
    }
}

extern "C" void kernel_launch(void* const* d_in, const int* in_sizes, int n_in,
                              void* d_out, int out_size, void* d_ws, size_t ws_size,
                              hipStream_t stream) {
    const float* x          = (const float*)d_in[0];
    const int*   dims       = (const int*)d_in[1];
    const int*   shifts     = (const int*)d_in[2];
    const int*   signs      = (const int*)d_in[3];
    const int*   apply_mask = (const int*)d_in[4];
    float* out = (float*)d_out;

    dim3 grid(B_ * C_ * D_), block(256);                // 2048 blocks
    shift3d_kernel<<<grid, block, 0, stream>>>(x, dims, shifts, signs, apply_mask, out);
}